// Round 2
// baseline (623.791 us; speedup 1.0000x reference)
//
#include <hip/hip_runtime.h>
#include <stdint.h>

// Problem constants
#define N_TOK 16384
#define FEAT  256
#define EMB   128
// OUT == 128

typedef float  f32x4  __attribute__((ext_vector_type(4)));
typedef __bf16 bf16x8 __attribute__((ext_vector_type(8)));
typedef short  s16x8  __attribute__((ext_vector_type(8)));

__device__ __forceinline__ unsigned short bf16_rne(float f) {
    union { float f; unsigned u; } v; v.f = f;
    unsigned u = v.u;
    return (unsigned short)((u + 0x7FFFu + ((u >> 16) & 1u)) >> 16);
}

__device__ __forceinline__ void async_cp16(const void* g, void* l) {
    __builtin_amdgcn_global_load_lds(
        (const __attribute__((address_space(1))) unsigned int*)g,
        (__attribute__((address_space(3))) unsigned int*)l, 16, 0, 0);
}

// ---------------- k0: W1 [256][128] -> W1T bf16 [128][256]; W2 [128][128] -> W2T bf16 [128][128]
__global__ void k0_transpose(const float* __restrict__ W1, const float* __restrict__ W2,
                             unsigned short* __restrict__ W1T, unsigned short* __restrict__ W2T)
{
    const int tid  = blockIdx.x * blockDim.x + threadIdx.x;
    const int nthr = gridDim.x * blockDim.x;
    for (int i = tid; i < FEAT * EMB; i += nthr) {
        const int r = i >> 7, c = i & 127;
        W1T[c * FEAT + r] = bf16_rne(W1[i]);
    }
    for (int i = tid; i < EMB * EMB; i += nthr) {
        const int r = i >> 7, c = i & 127;
        W2T[c * EMB + r] = bf16_rne(W2[i]);
    }
}

// ---------------- k1: h = x@W1 + b1 ; emit h_bf16 [N][128], hT_bf16 [128][N], d[N]=||h||^2
// grid 256 x 64 rows, 4 waves x 16 rows, MFMA 16x16x32, K=256 (8 ksteps)
// hT written via LDS transpose: 16B/lane stores, 128B-contiguous column segments.
__global__ __launch_bounds__(256) void k1_proj(
    const float* __restrict__ x, const unsigned short* __restrict__ W1T,
    const float* __restrict__ b1,
    unsigned short* __restrict__ h, unsigned short* __restrict__ hT,
    float* __restrict__ dg)
{
    const int lane = threadIdx.x & 63;
    const int wave = threadIdx.x >> 6;
    const int quad = lane >> 4;
    const int l15  = lane & 15;
    const int arow = blockIdx.x * 64 + wave * 16 + l15;   // A-frag row (m = lane&15)

    __shared__ unsigned short ldsT[128 * 68];  // [col][row] with pad 4 (stride 68 ushorts)

    const f32x4 zero4 = {0.f, 0.f, 0.f, 0.f};
    f32x4 acc[8];
    #pragma unroll
    for (int n0 = 0; n0 < 8; ++n0) acc[n0] = zero4;

    #pragma unroll
    for (int ks = 0; ks < 8; ++ks) {
        const float* xp = x + (size_t)arow * FEAT + ks * 32 + quad * 8;
        const float4 xa = *(const float4*)xp;
        const float4 xb = *(const float4*)(xp + 4);
        s16x8 at;
        at[0] = (short)bf16_rne(xa.x); at[1] = (short)bf16_rne(xa.y);
        at[2] = (short)bf16_rne(xa.z); at[3] = (short)bf16_rne(xa.w);
        at[4] = (short)bf16_rne(xb.x); at[5] = (short)bf16_rne(xb.y);
        at[6] = (short)bf16_rne(xb.z); at[7] = (short)bf16_rne(xb.w);
        const bf16x8 afr = __builtin_bit_cast(bf16x8, at);
        #pragma unroll
        for (int n0 = 0; n0 < 8; ++n0) {
            const bf16x8 bfr = *(const bf16x8*)(W1T + (size_t)(n0 * 16 + l15) * FEAT + ks * 32 + quad * 8);
            acc[n0] = __builtin_amdgcn_mfma_f32_16x16x32_bf16(afr, bfr, acc[n0], 0, 0, 0);
        }
    }

    const int rbase = blockIdx.x * 64 + wave * 16 + quad * 4;  // C rows = quad*4 + r
    float dpart[4] = {0.f, 0.f, 0.f, 0.f};
    #pragma unroll
    for (int n0 = 0; n0 < 8; ++n0) {
        const int col   = n0 * 16 + l15;
        const float bias = b1[col];
        unsigned short hb[4];
        #pragma unroll
        for (int r = 0; r < 4; ++r) {
            const float hv = acc[n0][r] + bias;
            const unsigned short q = bf16_rne(hv);
            hb[r] = q;
            union { unsigned u; float f; } bb; bb.u = ((unsigned)q) << 16;
            dpart[r] += bb.f * bb.f;                  // d from bf16-rounded h (diag consistency)
            h[(size_t)(rbase + r) * EMB + col] = q;
        }
        // stage transposed tile: [col][local row], 4 consecutive rows -> ushort4 (8B, aligned)
        ushort4 pk = make_ushort4(hb[0], hb[1], hb[2], hb[3]);
        *(ushort4*)&ldsT[col * 68 + wave * 16 + quad * 4] = pk;
    }
    #pragma unroll
    for (int r = 0; r < 4; ++r) {
        float v = dpart[r];
        v += __shfl_xor(v, 1);
        v += __shfl_xor(v, 2);
        v += __shfl_xor(v, 4);
        v += __shfl_xor(v, 8);
        if (l15 == 0) dg[rbase + r] = v;
    }

    __syncthreads();
    // coalesced hT writes: 1024 slots of 16B; slot -> (col = slot>>3, seg = slot&7)
    const int rbase0 = blockIdx.x * 64;
    #pragma unroll
    for (int i = 0; i < 4; ++i) {
        const int slot = i * 256 + threadIdx.x;
        const int c    = slot >> 3;
        const int seg  = slot & 7;
        const ushort4 a0 = *(const ushort4*)&ldsT[c * 68 + seg * 8];
        const ushort4 a1 = *(const ushort4*)&ldsT[c * 68 + seg * 8 + 4];
        ushort4 o[2] = {a0, a1};
        *(uint4*)&hT[(size_t)c * N_TOK + rbase0 + seg * 8] = *(const uint4*)o;
    }
}

// ---------------- k2: fused S = hI.hJ^T -> P = 2S/(di+dj) -> agg += P.hJ (flash-style)
// BM=128 rows/block (4 waves x 32), BN=64 per iter, runtime j-split -> partial agg out.
// LDS 32KB: R 16K | T 16K | P overlaid on R (per-wave 4K, XOR-swizzled, guarded by barrier B3).
__global__ __launch_bounds__(256, 4) void k2_graph(
    const unsigned short* __restrict__ h, const unsigned short* __restrict__ hT,
    const float* __restrict__ dg, float* __restrict__ aggp, int jshift)
{
    const int lane = threadIdx.x & 63;
    const int wave = threadIdx.x >> 6;
    const int quad = lane >> 4;
    const int l15  = lane & 15;

    const int rt   = blockIdx.x >> jshift;              // row tile
    const int jh   = blockIdx.x & ((1 << jshift) - 1);  // j-split index
    const int jchunk = N_TOK >> jshift;
    const int iters  = jchunk >> 6;
    const int wrow = rt * 128 + wave * 32;

    __shared__ __align__(16) unsigned char lds[32768];
    unsigned char* Rb = lds;
    unsigned char* Tb = lds + 16384;
    unsigned char* Pb = lds + wave * 4096;   // overlay on R region (safe after barrier B3)

    // Hoisted A-fragments (hI rows) + d_I, loaded once from global
    bf16x8 afrag[2][4];
    #pragma unroll
    for (int mt = 0; mt < 2; ++mt)
        #pragma unroll
        for (int ks = 0; ks < 4; ++ks)
            afrag[mt][ks] = *(const bf16x8*)(h + (size_t)(wrow + mt * 16 + l15) * EMB + ks * 32 + quad * 8);
    float dI[2][4];
    #pragma unroll
    for (int mt = 0; mt < 2; ++mt)
        #pragma unroll
        for (int r = 0; r < 4; ++r)
            dI[mt][r] = dg[wrow + mt * 16 + quad * 4 + r];

    const f32x4 zero4 = {0.f, 0.f, 0.f, 0.f};
    f32x4 acc[2][8];
    #pragma unroll
    for (int mt = 0; mt < 2; ++mt)
        #pragma unroll
        for (int n0 = 0; n0 < 8; ++n0) acc[mt][n0] = zero4;

    const int jbase = jh * jchunk;
    #pragma unroll 1
    for (int it = 0; it < iters; ++it) {
        const int j0 = jbase + it * 64;
        __syncthreads();   // B1: prev iter's matmul2 reads (T + P/R region) done before restage
        // Stage R: 16 chunks of 1KB (4 rows each); XOR-swizzle source so lane-linear LDS dest works
        #pragma unroll
        for (int c = 0; c < 4; ++c) {
            const int chunk = wave * 4 + c;
            const int rl = chunk * 4 + (lane >> 4);
            const int b  = (lane & 15) ^ (rl & 15);
            async_cp16(h + (size_t)(j0 + rl) * EMB + b * 8, Rb + chunk * 1024);
        }
        // Stage T: 16 chunks of 1KB (8 emb-rows each)
        #pragma unroll
        for (int c = 0; c < 4; ++c) {
            const int chunk = wave * 4 + c;
            const int cr = chunk * 8 + (lane >> 3);
            const int b  = (lane & 7) ^ (cr & 7);
            async_cp16(hT + (size_t)cr * N_TOK + j0 + b * 8, Tb + chunk * 1024);
        }
        float dJ[4];
        #pragma unroll
        for (int n0 = 0; n0 < 4; ++n0) dJ[n0] = dg[j0 + n0 * 16 + l15];
        __syncthreads();   // B2: staged data visible

        // matmul1: S[2m][4n] tiles, K=128
        f32x4 s[2][4];
        #pragma unroll
        for (int mt = 0; mt < 2; ++mt)
            #pragma unroll
            for (int n0 = 0; n0 < 4; ++n0) s[mt][n0] = zero4;
        #pragma unroll
        for (int ks = 0; ks < 4; ++ks) {
            bf16x8 bfr[4];
            #pragma unroll
            for (int n0 = 0; n0 < 4; ++n0) {
                const int n = n0 * 16 + l15;
                const int b = (ks * 4 + quad) ^ l15;
                bfr[n0] = *(const bf16x8*)(Rb + n * 256 + b * 16);
            }
            #pragma unroll
            for (int mt = 0; mt < 2; ++mt)
                #pragma unroll
                for (int n0 = 0; n0 < 4; ++n0)
                    s[mt][n0] = __builtin_amdgcn_mfma_f32_16x16x32_bf16(afrag[mt][ks], bfr[n0], s[mt][n0], 0, 0, 0);
        }

        __syncthreads();   // B3: all waves done reading R -> safe to overwrite with P

        // scale: P = 2*S/(d_i + d_j); store into overlaid per-wave region,
        // XOR-swizzled 16B blocks: blk' = (col>>3) ^ (row&7), stride 128B (2-way only)
        #pragma unroll
        for (int mt = 0; mt < 2; ++mt)
            #pragma unroll
            for (int n0 = 0; n0 < 4; ++n0)
                #pragma unroll
                for (int r = 0; r < 4; ++r) {
                    const int row = mt * 16 + quad * 4 + r;
                    const int col = n0 * 16 + l15;
                    const float denom = dI[mt][r] + dJ[n0];
                    const float pv = 2.0f * s[mt][n0][r] * __builtin_amdgcn_rcpf(denom);
                    const int blk = (col >> 3) ^ (row & 7);
                    *(unsigned short*)(Pb + row * 128 + blk * 16 + (col & 7) * 2) = bf16_rne(pv);
                }

        // matmul2: agg[2m][8n] += P[32x64] @ hJ[64x128]  (wave-local P; no barrier needed)
        #pragma unroll
        for (int ks2 = 0; ks2 < 2; ++ks2) {
            bf16x8 pfr[2];
            #pragma unroll
            for (int mt = 0; mt < 2; ++mt) {
                const int blk = (ks2 * 4 + quad) ^ (l15 & 7);
                pfr[mt] = *(const bf16x8*)(Pb + (mt * 16 + l15) * 128 + blk * 16);
            }
            #pragma unroll
            for (int n0 = 0; n0 < 8; ++n0) {
                const int n = n0 * 16 + l15;
                const int b = (ks2 * 4 + quad) ^ (l15 & 7);
                const bf16x8 bfr = *(const bf16x8*)(Tb + n * 128 + b * 16);
                #pragma unroll
                for (int mt = 0; mt < 2; ++mt)
                    acc[mt][n0] = __builtin_amdgcn_mfma_f32_16x16x32_bf16(pfr[mt], bfr, acc[mt][n0], 0, 0, 0);
            }
        }
    }

    float* op = aggp + (size_t)jh * N_TOK * EMB;
    #pragma unroll
    for (int mt = 0; mt < 2; ++mt)
        #pragma unroll
        for (int n0 = 0; n0 < 8; ++n0)
            #pragma unroll
            for (int r = 0; r < 4; ++r)
                op[(size_t)(wrow + mt * 16 + quad * 4 + r) * EMB + n0 * 16 + l15] = acc[mt][n0][r];
}

// ---------------- k3: out = relu((sum_p aggp[p]) @ W2 + b2) ; A-frags direct from global fp32
__global__ __launch_bounds__(256) void k3_out(
    const float* __restrict__ aggp, const unsigned short* __restrict__ W2T,
    const float* __restrict__ b2, float* __restrict__ out, int jsplit)
{
    const int lane = threadIdx.x & 63;
    const int wave = threadIdx.x >> 6;
    const int quad = lane >> 4;
    const int l15  = lane & 15;
    const int row0 = blockIdx.x * 64 + wave * 16;

    const f32x4 zero4 = {0.f, 0.f, 0.f, 0.f};
    f32x4 acc[8];
    #pragma unroll
    for (int n0 = 0; n0 < 8; ++n0) acc[n0] = zero4;

    #pragma unroll
    for (int ks = 0; ks < 4; ++ks) {
        const float* bp = aggp + (size_t)(row0 + l15) * EMB + ks * 32 + quad * 8;
        float av[8];
        #pragma unroll
        for (int j = 0; j < 8; ++j) av[j] = 0.f;
        #pragma unroll 1
        for (int p = 0; p < jsplit; ++p) {
            const float4 f1 = *(const float4*)(bp + (size_t)p * N_TOK * EMB);
            const float4 f2 = *(const float4*)(bp + (size_t)p * N_TOK * EMB + 4);
            av[0] += f1.x; av[1] += f1.y; av[2] += f1.z; av[3] += f1.w;
            av[4] += f2.x; av[5] += f2.y; av[6] += f2.z; av[7] += f2.w;
        }
        s16x8 at;
        #pragma unroll
        for (int j = 0; j < 8; ++j) at[j] = (short)bf16_rne(av[j]);
        const bf16x8 afr = __builtin_bit_cast(bf16x8, at);
        #pragma unroll
        for (int n0 = 0; n0 < 8; ++n0) {
            const bf16x8 bfr = *(const bf16x8*)(W2T + (size_t)(n0 * 16 + l15) * EMB + ks * 32 + quad * 8);
            acc[n0] = __builtin_amdgcn_mfma_f32_16x16x32_bf16(afr, bfr, acc[n0], 0, 0, 0);
        }
    }
    #pragma unroll
    for (int n0 = 0; n0 < 8; ++n0) {
        const int col  = n0 * 16 + l15;
        const float bias = b2[col];
        #pragma unroll
        for (int r = 0; r < 4; ++r) {
            float v = acc[n0][r] + bias;
            out[(size_t)(row0 + quad * 4 + r) * EMB + col] = v > 0.f ? v : 0.f;
        }
    }
}

extern "C" void kernel_launch(void* const* d_in, const int* in_sizes, int n_in,
                              void* d_out, int out_size, void* d_ws, size_t ws_size,
                              hipStream_t stream) {
    const float* x  = (const float*)d_in[0];
    const float* W1 = (const float*)d_in[1];
    const float* b1 = (const float*)d_in[2];
    const float* W2 = (const float*)d_in[3];
    const float* b2 = (const float*)d_in[4];
    float* out = (float*)d_out;

    char* ws = (char*)d_ws;
    // ws layout (bytes): h 4MB | hT 4MB | d 64KB | W1T 64KB | W2T 32KB | agg partials jsplit x 8MB
    unsigned short* h   = (unsigned short*)(ws);
    unsigned short* hT  = (unsigned short*)(ws + 4194304);
    float*          dg  = (float*)        (ws + 8388608);
    unsigned short* W1T = (unsigned short*)(ws + 8454144);
    unsigned short* W2T = (unsigned short*)(ws + 8519680);
    float*          agg = (float*)        (ws + 8552448);

    // jsplit=8 needs 8552448 + 8*8388608 = 75.7 MB of ws; fall back to 4 if unavailable.
    const size_t need8 = 8552448ull + 8ull * 8388608ull;
    const int jshift = (ws_size >= need8) ? 3 : 2;   // deterministic across calls
    const int jsplit = 1 << jshift;

    k0_transpose<<<dim3(16),  dim3(256), 0, stream>>>(W1, W2, W1T, W2T);
    k1_proj     <<<dim3(256), dim3(256), 0, stream>>>(x, W1T, b1, h, hT, dg);
    k2_graph    <<<dim3(128 << jshift), dim3(256), 0, stream>>>(h, hT, dg, agg, jshift);
    k3_out      <<<dim3(256), dim3(256), 0, stream>>>(agg, W2T, b2, out, jsplit);
}

// Round 3
// 277.066 us; speedup vs baseline: 2.2514x; 2.2514x over previous
//
#include <hip/hip_runtime.h>
#include <stdint.h>

// Problem constants
#define N_TOK 16384
#define FEAT  256
#define EMB   128
// OUT == 128

typedef float  f32x4  __attribute__((ext_vector_type(4)));
typedef __bf16 bf16x8 __attribute__((ext_vector_type(8)));
typedef short  s16x8  __attribute__((ext_vector_type(8)));

__device__ __forceinline__ unsigned short bf16_rne(float f) {
    union { float f; unsigned u; } v; v.f = f;
    unsigned u = v.u;
    return (unsigned short)((u + 0x7FFFu + ((u >> 16) & 1u)) >> 16);
}

__device__ __forceinline__ void async_cp16(const void* g, void* l) {
    __builtin_amdgcn_global_load_lds(
        (const __attribute__((address_space(1))) unsigned int*)g,
        (__attribute__((address_space(3))) unsigned int*)l, 16, 0, 0);
}

// ---------------- k0: W1 [256][128] -> W1T bf16 [128][256]; W2 [128][128] -> W2T bf16 [128][128]
__global__ void k0_transpose(const float* __restrict__ W1, const float* __restrict__ W2,
                             unsigned short* __restrict__ W1T, unsigned short* __restrict__ W2T)
{
    const int tid  = blockIdx.x * blockDim.x + threadIdx.x;
    const int nthr = gridDim.x * blockDim.x;
    for (int i = tid; i < FEAT * EMB; i += nthr) {
        const int r = i >> 7, c = i & 127;
        W1T[c * FEAT + r] = bf16_rne(W1[i]);
    }
    for (int i = tid; i < EMB * EMB; i += nthr) {
        const int r = i >> 7, c = i & 127;
        W2T[c * EMB + r] = bf16_rne(W2[i]);
    }
}

// ---------------- k1: h = x@W1 + b1 ; emit h_bf16 [N][128], hT_bf16 [128][N], d[N]=||h||^2
// grid 256 x 64 rows, 4 waves x 16 rows, MFMA 16x16x32, K=256 (8 ksteps)
// hT written via LDS transpose: 16B/lane stores, 128B-contiguous column segments.
__global__ __launch_bounds__(256) void k1_proj(
    const float* __restrict__ x, const unsigned short* __restrict__ W1T,
    const float* __restrict__ b1,
    unsigned short* __restrict__ h, unsigned short* __restrict__ hT,
    float* __restrict__ dg)
{
    const int lane = threadIdx.x & 63;
    const int wave = threadIdx.x >> 6;
    const int quad = lane >> 4;
    const int l15  = lane & 15;
    const int arow = blockIdx.x * 64 + wave * 16 + l15;   // A-frag row (m = lane&15)

    __shared__ unsigned short ldsT[128 * 68];  // [col][row] with pad 4 (stride 68 ushorts)

    const f32x4 zero4 = {0.f, 0.f, 0.f, 0.f};
    f32x4 acc[8];
    #pragma unroll
    for (int n0 = 0; n0 < 8; ++n0) acc[n0] = zero4;

    #pragma unroll
    for (int ks = 0; ks < 8; ++ks) {
        const float* xp = x + (size_t)arow * FEAT + ks * 32 + quad * 8;
        const float4 xa = *(const float4*)xp;
        const float4 xb = *(const float4*)(xp + 4);
        s16x8 at;
        at[0] = (short)bf16_rne(xa.x); at[1] = (short)bf16_rne(xa.y);
        at[2] = (short)bf16_rne(xa.z); at[3] = (short)bf16_rne(xa.w);
        at[4] = (short)bf16_rne(xb.x); at[5] = (short)bf16_rne(xb.y);
        at[6] = (short)bf16_rne(xb.z); at[7] = (short)bf16_rne(xb.w);
        const bf16x8 afr = __builtin_bit_cast(bf16x8, at);
        #pragma unroll
        for (int n0 = 0; n0 < 8; ++n0) {
            const bf16x8 bfr = *(const bf16x8*)(W1T + (size_t)(n0 * 16 + l15) * FEAT + ks * 32 + quad * 8);
            acc[n0] = __builtin_amdgcn_mfma_f32_16x16x32_bf16(afr, bfr, acc[n0], 0, 0, 0);
        }
    }

    const int rbase = blockIdx.x * 64 + wave * 16 + quad * 4;  // C rows = quad*4 + r
    float dpart[4] = {0.f, 0.f, 0.f, 0.f};
    #pragma unroll
    for (int n0 = 0; n0 < 8; ++n0) {
        const int col   = n0 * 16 + l15;
        const float bias = b1[col];
        unsigned short hb[4];
        #pragma unroll
        for (int r = 0; r < 4; ++r) {
            const float hv = acc[n0][r] + bias;
            const unsigned short q = bf16_rne(hv);
            hb[r] = q;
            union { unsigned u; float f; } bb; bb.u = ((unsigned)q) << 16;
            dpart[r] += bb.f * bb.f;                  // d from bf16-rounded h (diag consistency)
            h[(size_t)(rbase + r) * EMB + col] = q;
        }
        // stage transposed tile: [col][local row], 4 consecutive rows -> ushort4 (8B, aligned)
        ushort4 pk = make_ushort4(hb[0], hb[1], hb[2], hb[3]);
        *(ushort4*)&ldsT[col * 68 + wave * 16 + quad * 4] = pk;
    }
    #pragma unroll
    for (int r = 0; r < 4; ++r) {
        float v = dpart[r];
        v += __shfl_xor(v, 1);
        v += __shfl_xor(v, 2);
        v += __shfl_xor(v, 4);
        v += __shfl_xor(v, 8);
        if (l15 == 0) dg[rbase + r] = v;
    }

    __syncthreads();
    // coalesced hT writes: 1024 slots of 16B; slot -> (col = slot>>3, seg = slot&7)
    const int rbase0 = blockIdx.x * 64;
    #pragma unroll
    for (int i = 0; i < 4; ++i) {
        const int slot = i * 256 + threadIdx.x;
        const int c    = slot >> 3;
        const int seg  = slot & 7;
        const ushort4 a0 = *(const ushort4*)&ldsT[c * 68 + seg * 8];
        const ushort4 a1 = *(const ushort4*)&ldsT[c * 68 + seg * 8 + 4];
        ushort4 o[2] = {a0, a1};
        *(uint4*)&hT[(size_t)c * N_TOK + rbase0 + seg * 8] = *(const uint4*)o;
    }
}

// ---------------- k2: fused S = hI.hJ^T -> P = 2S/(di+dj) -> agg += P.hJ (flash-style)
// BM=128 rows/block (4 waves x 32), BN=64 per iter, runtime j-split -> partial agg out.
// ROUND-1 RESOURCE POINT, DO NOT SQUEEZE: 104 VGPR + 64 AGPR = 168 regs -> 3 waves/SIMD,
// LDS 51200 -> 3 blocks/CU. launch_bounds(256,4) in R2 forced VGPR=64 and the compiler
// rematerialized afrag from GLOBAL inside the K-loop: FETCH 14.5MB -> 1.46GB, 2.7x slower.
__global__ __launch_bounds__(256, 2) void k2_graph(
    const unsigned short* __restrict__ h, const unsigned short* __restrict__ hT,
    const float* __restrict__ dg, float* __restrict__ aggp, int jshift)
{
    const int lane = threadIdx.x & 63;
    const int wave = threadIdx.x >> 6;
    const int quad = lane >> 4;
    const int l15  = lane & 15;

    const int rt   = blockIdx.x >> jshift;              // row tile
    const int jh   = blockIdx.x & ((1 << jshift) - 1);  // j-split index
    const int jchunk = N_TOK >> jshift;
    const int iters  = jchunk >> 6;
    const int wrow = rt * 128 + wave * 32;

    // LDS: R (hJ row-major, swizzled) 16K | T (hJ^T, swizzled) 16K | P per-wave [32][72] bf16
    __shared__ __align__(16) unsigned char lds[51200];
    unsigned char* Rb = lds;
    unsigned char* Tb = lds + 16384;
    unsigned char* Pb = lds + 32768 + wave * 4608;

    // Hoisted A-fragments (hI rows) + d_I, loaded once from global
    bf16x8 afrag[2][4];
    #pragma unroll
    for (int mt = 0; mt < 2; ++mt)
        #pragma unroll
        for (int ks = 0; ks < 4; ++ks)
            afrag[mt][ks] = *(const bf16x8*)(h + (size_t)(wrow + mt * 16 + l15) * EMB + ks * 32 + quad * 8);
    float dI[2][4];
    #pragma unroll
    for (int mt = 0; mt < 2; ++mt)
        #pragma unroll
        for (int r = 0; r < 4; ++r)
            dI[mt][r] = dg[wrow + mt * 16 + quad * 4 + r];

    const f32x4 zero4 = {0.f, 0.f, 0.f, 0.f};
    f32x4 acc[2][8];
    #pragma unroll
    for (int mt = 0; mt < 2; ++mt)
        #pragma unroll
        for (int n0 = 0; n0 < 8; ++n0) acc[mt][n0] = zero4;

    const int jbase = jh * jchunk;
    #pragma unroll 1
    for (int it = 0; it < iters; ++it) {
        const int j0 = jbase + it * 64;
        __syncthreads();   // B1: prev iter's LDS reads done before restage
        // Stage R: 16 chunks of 1KB (4 rows each); XOR-swizzle source so lane-linear LDS dest works
        #pragma unroll
        for (int c = 0; c < 4; ++c) {
            const int chunk = wave * 4 + c;
            const int rl = chunk * 4 + (lane >> 4);
            const int b  = (lane & 15) ^ (rl & 15);
            async_cp16(h + (size_t)(j0 + rl) * EMB + b * 8, Rb + chunk * 1024);
        }
        // Stage T: 16 chunks of 1KB (8 emb-rows each)
        #pragma unroll
        for (int c = 0; c < 4; ++c) {
            const int chunk = wave * 4 + c;
            const int cr = chunk * 8 + (lane >> 3);
            const int b  = (lane & 7) ^ (cr & 7);
            async_cp16(hT + (size_t)cr * N_TOK + j0 + b * 8, Tb + chunk * 1024);
        }
        float dJ[4];
        #pragma unroll
        for (int n0 = 0; n0 < 4; ++n0) dJ[n0] = dg[j0 + n0 * 16 + l15];
        __syncthreads();   // B2: drains vmcnt -> staged data visible

        // matmul1: S[2m][4n] tiles, K=128
        f32x4 s[2][4];
        #pragma unroll
        for (int mt = 0; mt < 2; ++mt)
            #pragma unroll
            for (int n0 = 0; n0 < 4; ++n0) s[mt][n0] = zero4;
        #pragma unroll
        for (int ks = 0; ks < 4; ++ks) {
            bf16x8 bfr[4];
            #pragma unroll
            for (int n0 = 0; n0 < 4; ++n0) {
                const int n = n0 * 16 + l15;
                const int b = (ks * 4 + quad) ^ l15;
                bfr[n0] = *(const bf16x8*)(Rb + n * 256 + b * 16);
            }
            #pragma unroll
            for (int mt = 0; mt < 2; ++mt)
                #pragma unroll
                for (int n0 = 0; n0 < 4; ++n0)
                    s[mt][n0] = __builtin_amdgcn_mfma_f32_16x16x32_bf16(afrag[mt][ks], bfr[n0], s[mt][n0], 0, 0, 0);
        }

        // scale: P = 2*S/(d_i + d_j), write C-layout -> per-wave LDS (A-layout staging)
        #pragma unroll
        for (int mt = 0; mt < 2; ++mt)
            #pragma unroll
            for (int n0 = 0; n0 < 4; ++n0)
                #pragma unroll
                for (int r = 0; r < 4; ++r) {
                    const float denom = dI[mt][r] + dJ[n0];
                    const float pv = 2.0f * s[mt][n0][r] * __builtin_amdgcn_rcpf(denom);
                    *(unsigned short*)(Pb + (mt * 16 + quad * 4 + r) * 144 + (n0 * 16 + l15) * 2) = bf16_rne(pv);
                }

        // matmul2: agg[2m][8n] += P[32x64] @ hJ[64x128]  (wave-local P; no barrier needed)
        #pragma unroll
        for (int ks2 = 0; ks2 < 2; ++ks2) {
            bf16x8 pfr[2];
            #pragma unroll
            for (int mt = 0; mt < 2; ++mt)
                pfr[mt] = *(const bf16x8*)(Pb + (mt * 16 + l15) * 144 + ks2 * 64 + quad * 16);
            #pragma unroll
            for (int n0 = 0; n0 < 8; ++n0) {
                const int n = n0 * 16 + l15;
                const int b = (ks2 * 4 + quad) ^ (l15 & 7);
                const bf16x8 bfr = *(const bf16x8*)(Tb + n * 128 + b * 16);
                #pragma unroll
                for (int mt = 0; mt < 2; ++mt)
                    acc[mt][n0] = __builtin_amdgcn_mfma_f32_16x16x32_bf16(pfr[mt], bfr, acc[mt][n0], 0, 0, 0);
            }
        }
    }

    float* op = aggp + (size_t)jh * N_TOK * EMB;
    #pragma unroll
    for (int mt = 0; mt < 2; ++mt)
        #pragma unroll
        for (int n0 = 0; n0 < 8; ++n0)
            #pragma unroll
            for (int r = 0; r < 4; ++r)
                op[(size_t)(wrow + mt * 16 + quad * 4 + r) * EMB + n0 * 16 + l15] = acc[mt][n0][r];
}

// ---------------- k3: out = relu((sum_p aggp[p]) @ W2 + b2) ; A-frags direct from global fp32
__global__ __launch_bounds__(256) void k3_out(
    const float* __restrict__ aggp, const unsigned short* __restrict__ W2T,
    const float* __restrict__ b2, float* __restrict__ out, int jsplit)
{
    const int lane = threadIdx.x & 63;
    const int wave = threadIdx.x >> 6;
    const int quad = lane >> 4;
    const int l15  = lane & 15;
    const int row0 = blockIdx.x * 64 + wave * 16;

    const f32x4 zero4 = {0.f, 0.f, 0.f, 0.f};
    f32x4 acc[8];
    #pragma unroll
    for (int n0 = 0; n0 < 8; ++n0) acc[n0] = zero4;

    #pragma unroll
    for (int ks = 0; ks < 4; ++ks) {
        const float* bp = aggp + (size_t)(row0 + l15) * EMB + ks * 32 + quad * 8;
        float av[8];
        #pragma unroll
        for (int j = 0; j < 8; ++j) av[j] = 0.f;
        #pragma unroll 1
        for (int p = 0; p < jsplit; ++p) {
            const float4 f1 = *(const float4*)(bp + (size_t)p * N_TOK * EMB);
            const float4 f2 = *(const float4*)(bp + (size_t)p * N_TOK * EMB + 4);
            av[0] += f1.x; av[1] += f1.y; av[2] += f1.z; av[3] += f1.w;
            av[4] += f2.x; av[5] += f2.y; av[6] += f2.z; av[7] += f2.w;
        }
        s16x8 at;
        #pragma unroll
        for (int j = 0; j < 8; ++j) at[j] = (short)bf16_rne(av[j]);
        const bf16x8 afr = __builtin_bit_cast(bf16x8, at);
        #pragma unroll
        for (int n0 = 0; n0 < 8; ++n0) {
            const bf16x8 bfr = *(const bf16x8*)(W2T + (size_t)(n0 * 16 + l15) * EMB + ks * 32 + quad * 8);
            acc[n0] = __builtin_amdgcn_mfma_f32_16x16x32_bf16(afr, bfr, acc[n0], 0, 0, 0);
        }
    }
    #pragma unroll
    for (int n0 = 0; n0 < 8; ++n0) {
        const int col  = n0 * 16 + l15;
        const float bias = b2[col];
        #pragma unroll
        for (int r = 0; r < 4; ++r) {
            float v = acc[n0][r] + bias;
            out[(size_t)(row0 + quad * 4 + r) * EMB + col] = v > 0.f ? v : 0.f;
        }
    }
}

extern "C" void kernel_launch(void* const* d_in, const int* in_sizes, int n_in,
                              void* d_out, int out_size, void* d_ws, size_t ws_size,
                              hipStream_t stream) {
    const float* x  = (const float*)d_in[0];
    const float* W1 = (const float*)d_in[1];
    const float* b1 = (const float*)d_in[2];
    const float* W2 = (const float*)d_in[3];
    const float* b2 = (const float*)d_in[4];
    float* out = (float*)d_out;

    char* ws = (char*)d_ws;
    // ws layout (bytes): h 4MB | hT 4MB | d 64KB | W1T 64KB | W2T 32KB | agg partials jsplit x 8MB
    unsigned short* h   = (unsigned short*)(ws);
    unsigned short* hT  = (unsigned short*)(ws + 4194304);
    float*          dg  = (float*)        (ws + 8388608);
    unsigned short* W1T = (unsigned short*)(ws + 8454144);
    unsigned short* W2T = (unsigned short*)(ws + 8519680);
    float*          agg = (float*)        (ws + 8552448);

    // jsplit=8 needs 8552448 + 8*8388608 = 75.7 MB of ws; fall back to 4 if unavailable.
    const size_t need8 = 8552448ull + 8ull * 8388608ull;
    const int jshift = (ws_size >= need8) ? 3 : 2;   // deterministic across calls
    const int jsplit = 1 << jshift;

    k0_transpose<<<dim3(16),  dim3(256), 0, stream>>>(W1, W2, W1T, W2T);
    k1_proj     <<<dim3(256), dim3(256), 0, stream>>>(x, W1T, b1, h, hT, dg);
    k2_graph    <<<dim3(128 << jshift), dim3(256), 0, stream>>>(h, hT, dg, agg, jshift);
    k3_out      <<<dim3(256), dim3(256), 0, stream>>>(agg, W2T, b2, out, jsplit);
}

// Round 4
// 247.797 us; speedup vs baseline: 2.5173x; 1.1181x over previous
//
#include <hip/hip_runtime.h>
#include <stdint.h>

// Problem constants
#define N_TOK 16384
#define FEAT  256
#define EMB   128
#define JSPLIT 6   // grid 128*6=768 = exactly 3 blocks/CU at the 170-reg point
// OUT == 128

typedef float  f32x4  __attribute__((ext_vector_type(4)));
typedef __bf16 bf16x8 __attribute__((ext_vector_type(8)));
typedef short  s16x8  __attribute__((ext_vector_type(8)));

__device__ __forceinline__ unsigned short bf16_rne(float f) {
    union { float f; unsigned u; } v; v.f = f;
    unsigned u = v.u;
    return (unsigned short)((u + 0x7FFFu + ((u >> 16) & 1u)) >> 16);
}

__device__ __forceinline__ void async_cp16(const void* g, void* l) {
    __builtin_amdgcn_global_load_lds(
        (const __attribute__((address_space(1))) unsigned int*)g,
        (__attribute__((address_space(3))) unsigned int*)l, 16, 0, 0);
}

// ---------------- k0: W1 [256][128] -> W1T bf16 [128][256]; W2 [128][128] -> W2T bf16 [128][128]
__global__ void k0_transpose(const float* __restrict__ W1, const float* __restrict__ W2,
                             unsigned short* __restrict__ W1T, unsigned short* __restrict__ W2T)
{
    const int tid  = blockIdx.x * blockDim.x + threadIdx.x;
    const int nthr = gridDim.x * blockDim.x;
    for (int i = tid; i < FEAT * EMB; i += nthr) {
        const int r = i >> 7, c = i & 127;
        W1T[c * FEAT + r] = bf16_rne(W1[i]);
    }
    for (int i = tid; i < EMB * EMB; i += nthr) {
        const int r = i >> 7, c = i & 127;
        W2T[c * EMB + r] = bf16_rne(W2[i]);
    }
}

// ---------------- k1: h = x@W1 + b1 ; emit h_bf16 [N][128], hT_bf16 [128][N], d[N]=||h||^2
__global__ __launch_bounds__(256) void k1_proj(
    const float* __restrict__ x, const unsigned short* __restrict__ W1T,
    const float* __restrict__ b1,
    unsigned short* __restrict__ h, unsigned short* __restrict__ hT,
    float* __restrict__ dg)
{
    const int lane = threadIdx.x & 63;
    const int wave = threadIdx.x >> 6;
    const int quad = lane >> 4;
    const int l15  = lane & 15;
    const int arow = blockIdx.x * 64 + wave * 16 + l15;   // A-frag row (m = lane&15)

    __shared__ unsigned short ldsT[128 * 68];  // [col][row] pad 4 (stride 68 ushorts)

    const f32x4 zero4 = {0.f, 0.f, 0.f, 0.f};
    f32x4 acc[8];
    #pragma unroll
    for (int n0 = 0; n0 < 8; ++n0) acc[n0] = zero4;

    #pragma unroll
    for (int ks = 0; ks < 8; ++ks) {
        const float* xp = x + (size_t)arow * FEAT + ks * 32 + quad * 8;
        const float4 xa = *(const float4*)xp;
        const float4 xb = *(const float4*)(xp + 4);
        s16x8 at;
        at[0] = (short)bf16_rne(xa.x); at[1] = (short)bf16_rne(xa.y);
        at[2] = (short)bf16_rne(xa.z); at[3] = (short)bf16_rne(xa.w);
        at[4] = (short)bf16_rne(xb.x); at[5] = (short)bf16_rne(xb.y);
        at[6] = (short)bf16_rne(xb.z); at[7] = (short)bf16_rne(xb.w);
        const bf16x8 afr = __builtin_bit_cast(bf16x8, at);
        #pragma unroll
        for (int n0 = 0; n0 < 8; ++n0) {
            const bf16x8 bfr = *(const bf16x8*)(W1T + (size_t)(n0 * 16 + l15) * FEAT + ks * 32 + quad * 8);
            acc[n0] = __builtin_amdgcn_mfma_f32_16x16x32_bf16(afr, bfr, acc[n0], 0, 0, 0);
        }
    }

    const int rbase = blockIdx.x * 64 + wave * 16 + quad * 4;  // C rows = quad*4 + r
    float dpart[4] = {0.f, 0.f, 0.f, 0.f};
    #pragma unroll
    for (int n0 = 0; n0 < 8; ++n0) {
        const int col   = n0 * 16 + l15;
        const float bias = b1[col];
        unsigned short hb[4];
        #pragma unroll
        for (int r = 0; r < 4; ++r) {
            const float hv = acc[n0][r] + bias;
            const unsigned short q = bf16_rne(hv);
            hb[r] = q;
            union { unsigned u; float f; } bb; bb.u = ((unsigned)q) << 16;
            dpart[r] += bb.f * bb.f;                  // d from bf16-rounded h (diag consistency)
            h[(size_t)(rbase + r) * EMB + col] = q;
        }
        ushort4 pk = make_ushort4(hb[0], hb[1], hb[2], hb[3]);
        *(ushort4*)&ldsT[col * 68 + wave * 16 + quad * 4] = pk;
    }
    #pragma unroll
    for (int r = 0; r < 4; ++r) {
        float v = dpart[r];
        v += __shfl_xor(v, 1);
        v += __shfl_xor(v, 2);
        v += __shfl_xor(v, 4);
        v += __shfl_xor(v, 8);
        if (l15 == 0) dg[rbase + r] = v;
    }

    __syncthreads();
    const int rbase0 = blockIdx.x * 64;
    #pragma unroll
    for (int i = 0; i < 4; ++i) {
        const int slot = i * 256 + threadIdx.x;
        const int c    = slot >> 3;
        const int seg  = slot & 7;
        const ushort4 a0 = *(const ushort4*)&ldsT[c * 68 + seg * 8];
        const ushort4 a1 = *(const ushort4*)&ldsT[c * 68 + seg * 8 + 4];
        ushort4 o[2] = {a0, a1};
        *(uint4*)&hT[(size_t)c * N_TOK + rbase0 + seg * 8] = *(const uint4*)o;
    }
}

// ---------------- k2: fused S = hI.hJ^T -> P = 2S/(di+dj) -> agg += P.hJ (flash-style)
// BM=128 (4 waves x 32 rows), BN=64/iter. Occupancy engineering (R3 post-mortem):
// R1/R3 used ~200 total regs (104 arch + ~96 AGPR) -> floor(512/200)=2 waves/SIMD -> 2 blocks/CU.
// Fix: sequence matmul1 by n0-halves so only 16 S-AGPRs are live (B-frags still read once each),
// consume each P-half immediately in the matching matmul2 k-half (per-wave 2KB P, reused).
// Target <=170 total regs (launch_bounds(256,3)) + LDS 40960 -> 3 blocks/CU.
__global__ __launch_bounds__(256, 3) void k2_graph(
    const unsigned short* __restrict__ h, const unsigned short* __restrict__ hT,
    const float* __restrict__ dg, float* __restrict__ aggp)
{
    const int lane = threadIdx.x & 63;
    const int wave = threadIdx.x >> 6;
    const int quad = lane >> 4;
    const int l15  = lane & 15;

    const int rt = blockIdx.x / JSPLIT;            // row tile 0..127
    const int jh = blockIdx.x - rt * JSPLIT;       // j-split index 0..5
    // global j-tile (64 rows each) range for this split: [it0, it1)
    const int it0 = (jh * 256) / JSPLIT;
    const int it1 = ((jh + 1) * 256) / JSPLIT;
    const int wrow = rt * 128 + wave * 32;

    // LDS: R 16K | T 16K | P per-wave 2KB (32 rows x 32 cols bf16, swizzled 16B blocks)
    __shared__ __align__(16) unsigned char lds[40960];
    unsigned char* Rb = lds;
    unsigned char* Tb = lds + 16384;
    unsigned char* Pb = lds + 32768 + wave * 2048;

    // Hoisted A-fragments (hI rows) + 0.5*d_I (fold the 2/(di+dj) -> 1/(di/2+dj/2))
    bf16x8 afrag[2][4];
    #pragma unroll
    for (int mt = 0; mt < 2; ++mt)
        #pragma unroll
        for (int ks = 0; ks < 4; ++ks)
            afrag[mt][ks] = *(const bf16x8*)(h + (size_t)(wrow + mt * 16 + l15) * EMB + ks * 32 + quad * 8);
    float dI2[2][4];
    #pragma unroll
    for (int mt = 0; mt < 2; ++mt)
        #pragma unroll
        for (int r = 0; r < 4; ++r)
            dI2[mt][r] = 0.5f * dg[wrow + mt * 16 + quad * 4 + r];

    const f32x4 zero4 = {0.f, 0.f, 0.f, 0.f};
    f32x4 acc[2][8];
    #pragma unroll
    for (int mt = 0; mt < 2; ++mt)
        #pragma unroll
        for (int n0 = 0; n0 < 8; ++n0) acc[mt][n0] = zero4;

    #pragma unroll 1
    for (int it = it0; it < it1; ++it) {
        const int j0 = it * 64;
        __syncthreads();   // B1: prev iter's LDS reads done before restage
        // Stage R (hJ rows): 16 chunks of 1KB; XOR-swizzled source, lane-linear LDS dest
        #pragma unroll
        for (int c = 0; c < 4; ++c) {
            const int chunk = wave * 4 + c;
            const int rl = chunk * 4 + (lane >> 4);
            const int b  = (lane & 15) ^ (rl & 15);
            async_cp16(h + (size_t)(j0 + rl) * EMB + b * 8, Rb + chunk * 1024);
        }
        // Stage T (hJ^T): 16 chunks of 1KB
        #pragma unroll
        for (int c = 0; c < 4; ++c) {
            const int chunk = wave * 4 + c;
            const int cr = chunk * 8 + (lane >> 3);
            const int b  = (lane & 7) ^ (cr & 7);
            async_cp16(hT + (size_t)cr * N_TOK + j0 + b * 8, Tb + chunk * 1024);
        }
        float dJ2[4];
        #pragma unroll
        for (int n0 = 0; n0 < 4; ++n0) dJ2[n0] = 0.5f * dg[j0 + n0 * 16 + l15];
        __syncthreads();   // B2: drains vmcnt -> staged data visible

        // Two half-iterations: n0-half of S -> P-half -> matmul2 k-half.
        #pragma unroll
        for (int h2 = 0; h2 < 2; ++h2) {
            // matmul1 half: S tiles n0 = h2*2 + {0,1}, K=128. Only 16 S-AGPRs live.
            f32x4 s[2][2];
            #pragma unroll
            for (int mt = 0; mt < 2; ++mt)
                #pragma unroll
                for (int nn = 0; nn < 2; ++nn) s[mt][nn] = zero4;
            #pragma unroll
            for (int ks = 0; ks < 4; ++ks) {
                bf16x8 bfr[2];
                #pragma unroll
                for (int nn = 0; nn < 2; ++nn) {
                    const int n = (h2 * 2 + nn) * 16 + l15;
                    const int b = (ks * 4 + quad) ^ l15;
                    bfr[nn] = *(const bf16x8*)(Rb + n * 256 + b * 16);
                }
                #pragma unroll
                for (int mt = 0; mt < 2; ++mt)
                    #pragma unroll
                    for (int nn = 0; nn < 2; ++nn)
                        s[mt][nn] = __builtin_amdgcn_mfma_f32_16x16x32_bf16(afrag[mt][ks], bfr[nn], s[mt][nn], 0, 0, 0);
            }

            // scale: P = s / (di/2 + dj/2); write into per-wave 2KB chunk.
            // layout: addr = row*64 + (((col>>3)^(row&3))&3)*16 + (col&7)*2  (2-way worst case)
            #pragma unroll
            for (int mt = 0; mt < 2; ++mt)
                #pragma unroll
                for (int nn = 0; nn < 2; ++nn)
                    #pragma unroll
                    for (int r = 0; r < 4; ++r) {
                        const int row = mt * 16 + quad * 4 + r;
                        const int col = nn * 16 + l15;          // 0..31 within half
                        const float denom = dI2[mt][r] + dJ2[h2 * 2 + nn];
                        const float pv = s[mt][nn][r] * __builtin_amdgcn_rcpf(denom);
                        const int blk = ((col >> 3) ^ (row & 3)) & 3;
                        *(__bf16*)(Pb + row * 64 + blk * 16 + (col & 7) * 2) = (__bf16)pv;
                    }

            // matmul2 k-half: agg += P_half[32x32] @ hJ[h2*32..+32][128]
            // (wave-local P: compiler orders ds ops via aliasing, no barrier needed)
            bf16x8 pfr[2];
            #pragma unroll
            for (int mt = 0; mt < 2; ++mt) {
                const int row = mt * 16 + l15;
                const int blk = (quad ^ (l15 & 3)) & 3;
                pfr[mt] = *(const bf16x8*)(Pb + row * 64 + blk * 16);
            }
            #pragma unroll
            for (int n0 = 0; n0 < 8; ++n0) {
                const int n = n0 * 16 + l15;
                const int b = (h2 * 4 + quad) ^ (l15 & 7);
                const bf16x8 bfr = *(const bf16x8*)(Tb + n * 128 + b * 16);
                #pragma unroll
                for (int mt = 0; mt < 2; ++mt)
                    acc[mt][n0] = __builtin_amdgcn_mfma_f32_16x16x32_bf16(pfr[mt], bfr, acc[mt][n0], 0, 0, 0);
            }
        }
    }

    float* op = aggp + (size_t)jh * N_TOK * EMB;
    #pragma unroll
    for (int mt = 0; mt < 2; ++mt)
        #pragma unroll
        for (int n0 = 0; n0 < 8; ++n0)
            #pragma unroll
            for (int r = 0; r < 4; ++r)
                op[(size_t)(wrow + mt * 16 + quad * 4 + r) * EMB + n0 * 16 + l15] = acc[mt][n0][r];
}

// ---------------- k3: out = relu((sum_p aggp[p]) @ W2 + b2)
__global__ __launch_bounds__(256) void k3_out(
    const float* __restrict__ aggp, const unsigned short* __restrict__ W2T,
    const float* __restrict__ b2, float* __restrict__ out)
{
    const int lane = threadIdx.x & 63;
    const int wave = threadIdx.x >> 6;
    const int quad = lane >> 4;
    const int l15  = lane & 15;
    const int row0 = blockIdx.x * 64 + wave * 16;

    const f32x4 zero4 = {0.f, 0.f, 0.f, 0.f};
    f32x4 acc[8];
    #pragma unroll
    for (int n0 = 0; n0 < 8; ++n0) acc[n0] = zero4;

    #pragma unroll
    for (int ks = 0; ks < 4; ++ks) {
        const float* bp = aggp + (size_t)(row0 + l15) * EMB + ks * 32 + quad * 8;
        float av[8];
        #pragma unroll
        for (int j = 0; j < 8; ++j) av[j] = 0.f;
        #pragma unroll
        for (int p = 0; p < JSPLIT; ++p) {
            const float4 f1 = *(const float4*)(bp + (size_t)p * N_TOK * EMB);
            const float4 f2 = *(const float4*)(bp + (size_t)p * N_TOK * EMB + 4);
            av[0] += f1.x; av[1] += f1.y; av[2] += f1.z; av[3] += f1.w;
            av[4] += f2.x; av[5] += f2.y; av[6] += f2.z; av[7] += f2.w;
        }
        s16x8 at;
        #pragma unroll
        for (int j = 0; j < 8; ++j) at[j] = (short)bf16_rne(av[j]);
        const bf16x8 afr = __builtin_bit_cast(bf16x8, at);
        #pragma unroll
        for (int n0 = 0; n0 < 8; ++n0) {
            const bf16x8 bfr = *(const bf16x8*)(W2T + (size_t)(n0 * 16 + l15) * EMB + ks * 32 + quad * 8);
            acc[n0] = __builtin_amdgcn_mfma_f32_16x16x32_bf16(afr, bfr, acc[n0], 0, 0, 0);
        }
    }
    #pragma unroll
    for (int n0 = 0; n0 < 8; ++n0) {
        const int col  = n0 * 16 + l15;
        const float bias = b2[col];
        #pragma unroll
        for (int r = 0; r < 4; ++r) {
            float v = acc[n0][r] + bias;
            out[(size_t)(row0 + quad * 4 + r) * EMB + col] = v > 0.f ? v : 0.f;
        }
    }
}

extern "C" void kernel_launch(void* const* d_in, const int* in_sizes, int n_in,
                              void* d_out, int out_size, void* d_ws, size_t ws_size,
                              hipStream_t stream) {
    const float* x  = (const float*)d_in[0];
    const float* W1 = (const float*)d_in[1];
    const float* b1 = (const float*)d_in[2];
    const float* W2 = (const float*)d_in[3];
    const float* b2 = (const float*)d_in[4];
    float* out = (float*)d_out;

    char* ws = (char*)d_ws;
    // ws layout (bytes): h 4MB | hT 4MB | d 64KB | W1T 64KB | W2T 32KB | agg partials JSPLIT x 8MB
    unsigned short* h   = (unsigned short*)(ws);
    unsigned short* hT  = (unsigned short*)(ws + 4194304);
    float*          dg  = (float*)        (ws + 8388608);
    unsigned short* W1T = (unsigned short*)(ws + 8454144);
    unsigned short* W2T = (unsigned short*)(ws + 8519680);
    float*          agg = (float*)        (ws + 8552448);  // JSPLIT*8MB = 48MB -> total ~56.6MB (<R3's 75.7MB use)

    k0_transpose<<<dim3(16),  dim3(256), 0, stream>>>(W1, W2, W1T, W2T);
    k1_proj     <<<dim3(256), dim3(256), 0, stream>>>(x, W1T, b1, h, hT, dg);
    k2_graph    <<<dim3(128 * JSPLIT), dim3(256), 0, stream>>>(h, hT, dg, agg);
    k3_out      <<<dim3(256), dim3(256), 0, stream>>>(agg, W2T, b2, out);
}